// Round 9
// baseline (231.941 us; speedup 1.0000x reference)
//
#include <hip/hip_runtime.h>
#include <hip/hip_bf16.h>
#include <math.h>

#define Bdim 2
#define Cdim 256
#define Ndim 4096
#define HEADS 4
#define HDim 64

typedef _Float16 half8 __attribute__((ext_vector_type(8)));
typedef _Float16 half4 __attribute__((ext_vector_type(4)));
typedef float f32x4 __attribute__((ext_vector_type(4)));

// ws layout in floats
static const size_t WS_STATS  = 0;        // 64*2 -> pad 256
static const size_t WS_WTPROJ = 256;      // 256*256 f32 -> ends 65792
static const size_t WS_WHQ    = 65792;    // 768*256 f16 = 98304 fl -> ends 164096
static const size_t WS_HN     = 164096;   // 2*256*4096 f32 (attn out) -> ends 2261248
static const size_t WS_HNT    = 2261248;  // 2*4096*256 f16 -> ends 3309824
static const size_t WS_QT     = 3309824;  // 2*4*4096*64 f16 -> ends 4358400
static const size_t WS_KT     = 4358400;  // -> ends 5406976
static const size_t WS_VF     = 5406976;  // 2*256*4096 f16 -> ends 6455552 (~25.8 MB)

// q scale: 1/sqrt(64) * log2(e); MFMA acc init -8.65617 gives P = e^(S_true-6),
// the e^-6 cancels in the normalize.
#define QSCALE 0.18033688f
#define SINIT  -8.65617025f

// ---------------- group-norm stats ----------------
__global__ __launch_bounds__(256) void gn_stats_k(const float* __restrict__ x,
                                                  float* __restrict__ stats) {
    int g = blockIdx.x;
    const float4* p4 = (const float4*)(x + (size_t)g * 32768);
    int tid = threadIdx.x;
    float s = 0.f, ss = 0.f;
#pragma unroll 8
    for (int w = 0; w < 32; w++) {
        float4 v = p4[tid + w * 256];
        s += v.x + v.y + v.z + v.w;
        ss += v.x * v.x + v.y * v.y + v.z * v.z + v.w * v.w;
    }
#pragma unroll
    for (int m = 1; m < 64; m <<= 1) {
        s += __shfl_xor(s, m);
        ss += __shfl_xor(ss, m);
    }
    __shared__ float ws_s[4], ws_ss[4];
    int wid = tid >> 6, lane = tid & 63;
    if (lane == 0) { ws_s[wid] = s; ws_ss[wid] = ss; }
    __syncthreads();
    if (tid == 0) {
        float ts = ws_s[0] + ws_s[1] + ws_s[2] + ws_s[3];
        float tss = ws_ss[0] + ws_ss[1] + ws_ss[2] + ws_ss[3];
        float mean = ts * (1.0f / 32768.0f);
        float var = tss * (1.0f / 32768.0f) - mean * mean;
        stats[2 * g] = mean;
        stats[2 * g + 1] = rsqrtf(var + 1e-5f);
    }
}

// ---------------- GN apply + transpose -> hnT[b][n][c] f16 ----------------
__global__ __launch_bounds__(256) void gnT_k(const float* __restrict__ x,
                                             const float* __restrict__ stats,
                                             const float* __restrict__ scale,
                                             const float* __restrict__ bias,
                                             _Float16* __restrict__ hnT) {
    __shared__ float t[64][68];
    const int tid = threadIdx.x;
    const int n0 = blockIdx.x << 6, c0 = blockIdx.y << 6, bz = blockIdx.z;
    const int cr = tid >> 2, q4 = tid & 3;
    const int c = c0 + cr;
    const int g = bz * 32 + (c >> 3);
    const float sc = stats[2 * g + 1] * scale[c];
    const float bi = bias[c] - stats[2 * g] * sc;
    const float* base = x + ((size_t)(bz * 256 + c)) * Ndim + n0;
#pragma unroll
    for (int k = 0; k < 4; k++) {
        int j = k * 4 + q4;
        float4 v = *(const float4*)(base + j * 4);
        v.x = v.x * sc + bi; v.y = v.y * sc + bi; v.z = v.z * sc + bi; v.w = v.w * sc + bi;
        *(float4*)&t[cr][j * 4] = v;
    }
    __syncthreads();
    const int nr = tid >> 2, ch = tid & 3;
    half8 o0, o1;
#pragma unroll
    for (int j = 0; j < 8; j++) o0[j] = (_Float16)t[ch * 16 + j][nr];
#pragma unroll
    for (int j = 0; j < 8; j++) o1[j] = (_Float16)t[ch * 16 + 8 + j][nr];
    _Float16* dst = hnT + ((size_t)bz * Ndim + n0 + nr) * 256 + c0 + ch * 16;
    *(half8*)(dst) = o0;
    *(half8*)(dst + 8) = o1;
}

// ---------------- w_qkv f32 -> f16 (QSCALE folded for q rows) ----------------
__global__ __launch_bounds__(256) void wcvt_k(const float* __restrict__ w,
                                              _Float16* __restrict__ wh) {
    int i = blockIdx.x * 256 + threadIdx.x;
    float v = w[i];
    if ((i >> 8) < 256) v *= QSCALE;
    wh[i] = (_Float16)v;
}

// ---------------- weight transpose (w_proj only): W[O][C] -> WT[C][O] --------
__global__ __launch_bounds__(256) void tpose_k(const float* __restrict__ W,
                                               float* __restrict__ WT,
                                               int O, int Cc) {
    __shared__ float t[32][33];
    int c0 = blockIdx.x * 32, o0 = blockIdx.y * 32;
    int tx = threadIdx.x, ty = threadIdx.y;
#pragma unroll
    for (int k = 0; k < 4; k++) {
        int o = o0 + ty + k * 8;
        t[ty + k * 8][tx] = W[(size_t)o * Cc + c0 + tx];
    }
    __syncthreads();
#pragma unroll
    for (int k = 0; k < 4; k++) {
        int c = c0 + ty + k * 8;
        WT[(size_t)c * O + o0 + tx] = t[tx][ty + k * 8];
    }
}

// ---------------- QKV GEMM, f16 MFMA ----------------
__global__ __launch_bounds__(256) void gemm_qkv16_k(const _Float16* __restrict__ wh,
                                                    const _Float16* __restrict__ hnT,
                                                    _Float16* __restrict__ qT,
                                                    _Float16* __restrict__ kT,
                                                    _Float16* __restrict__ vF) {
    __shared__ __align__(16) char smem[32768];  // W dbuf 2x8K @0, X dbuf 2x8K @16384
    const int tid = threadIdx.x, w = tid >> 6, lane = tid & 63;
    const int a = lane >> 4, b_ = lane & 15;
    const int wo = w >> 1, wn = w & 1;
    const int n0 = blockIdx.x << 7, o0 = blockIdx.y << 7, bz = blockIdx.z;

    const int srow = tid >> 1, su = (tid & 1) << 1;
    const _Float16* wg = wh + (size_t)(o0 + srow) * 256 + (su << 3);
    const _Float16* xg = hnT + ((size_t)(bz * Ndim + n0 + srow)) * 256 + (su << 3);
    const int wd0 = srow * 64 + ((su ^ (srow & 3)) << 4);
    const int wd1 = srow * 64 + (((su + 1) ^ (srow & 3)) << 4);

    {
        half8 a0 = *(const half8*)(wg), a1 = *(const half8*)(wg + 8);
        half8 b0 = *(const half8*)(xg), b1 = *(const half8*)(xg + 8);
        *(half8*)(smem + wd0) = a0; *(half8*)(smem + wd1) = a1;
        *(half8*)(smem + 16384 + wd0) = b0; *(half8*)(smem + 16384 + wd1) = b1;
    }
    __syncthreads();

    f32x4 acc[4][4] = {};
    const int fa = (a ^ (b_ & 3)) << 4;
    int arow[4], brow[4];
#pragma unroll
    for (int t = 0; t < 4; t++) {
        arow[t] = (wo * 64 + t * 16 + b_) * 64 + fa;
        brow[t] = 16384 + (wn * 64 + t * 16 + b_) * 64 + fa;
    }

    for (int kk = 0; kk < 8; kk++) {
        const int cur = (kk & 1) * 8192;
        half8 nw0, nw1, nx0, nx1;
        const bool pf = (kk < 7);
        if (pf) {
            const _Float16* wp = wg + (kk + 1) * 32;
            const _Float16* xp = xg + (kk + 1) * 32;
            nw0 = *(const half8*)(wp); nw1 = *(const half8*)(wp + 8);
            nx0 = *(const half8*)(xp); nx1 = *(const half8*)(xp + 8);
        }
        half8 af[4], bf[4];
#pragma unroll
        for (int t = 0; t < 4; t++) {
            af[t] = *(const half8*)(smem + cur + arow[t]);
            bf[t] = *(const half8*)(smem + cur + brow[t]);
        }
#pragma unroll
        for (int i = 0; i < 4; i++)
#pragma unroll
            for (int j = 0; j < 4; j++)
                acc[i][j] = __builtin_amdgcn_mfma_f32_16x16x32_f16(af[i], bf[j], acc[i][j], 0, 0, 0);
        if (pf) {
            const int nxt = cur ^ 8192;
            *(half8*)(smem + nxt + wd0) = nw0; *(half8*)(smem + nxt + wd1) = nw1;
            *(half8*)(smem + 16384 + nxt + wd0) = nx0; *(half8*)(smem + 16384 + nxt + wd1) = nx1;
        }
        __syncthreads();
    }

    if (o0 < 512) {
        // q/k: LDS-bounce to [n][o] f16 (8B-unit XOR swizzle), then coalesced rows
#pragma unroll
        for (int ot = 0; ot < 4; ot++) {
#pragma unroll
            for (int nt = 0; nt < 4; nt++) {
                int n = wn * 64 + nt * 16 + b_;
                int u = wo * 16 + ot * 4 + a;  // 8B unit along o (o = u*4 + r)
                half4 hv;
                hv[0] = (_Float16)acc[ot][nt][0]; hv[1] = (_Float16)acc[ot][nt][1];
                hv[2] = (_Float16)acc[ot][nt][2]; hv[3] = (_Float16)acc[ot][nt][3];
                *(half4*)(smem + n * 256 + ((u ^ (n & 31)) << 3)) = hv;
            }
        }
        __syncthreads();
        _Float16* dst = (o0 >= 256) ? kT : qT;
        const int headbase = (o0 >> 6) & 3;
#pragma unroll
        for (int hsel = 0; hsel < 2; hsel++) {
            _Float16* hb = dst + ((size_t)(bz * 4 + headbase + hsel)) * (Ndim * 64);
#pragma unroll
            for (int p = 0; p < 4; p++) {
                int n = p * 32 + (tid >> 3), j = tid & 7;
                int u0 = hsel * 16 + j * 2;
                half4 lo = *(const half4*)(smem + n * 256 + ((u0 ^ (n & 31)) << 3));
                half4 hi = *(const half4*)(smem + n * 256 + (((u0 + 1) ^ (n & 31)) << 3));
                half8 o8;
                o8[0] = lo[0]; o8[1] = lo[1]; o8[2] = lo[2]; o8[3] = lo[3];
                o8[4] = hi[0]; o8[5] = hi[1]; o8[6] = hi[2]; o8[7] = hi[3];
                *(half8*)(hb + (size_t)(n0 + n) * 64 + j * 8) = o8;
            }
        }
    } else {
        // v: direct b16 stores (16-lane 32B segments)
        _Float16* vb = vF + ((size_t)bz * 256 + (o0 - 512)) * Ndim;
#pragma unroll
        for (int ot = 0; ot < 4; ot++)
#pragma unroll
            for (int nt = 0; nt < 4; nt++)
#pragma unroll
                for (int r = 0; r < 4; r++)
                    vb[(size_t)(wo * 64 + ot * 16 + a * 4 + r) * Ndim +
                       n0 + wn * 64 + nt * 16 + b_] = (_Float16)acc[ot][nt][r];
    }
}

// ---------------- flash attention: register-direct K/V, k-split waves --------
// 512 blocks (XCD-swizzled). Wave w owns keys [w*1024,(w+1)*1024) x ALL 64 q.
// K/V fragments load straight from global (L2-resident) into regs; NO LDS and
// NO barriers in the main loop. Static-max softmax => per-wave partial (O, l)
// sum directly; one-time LDS combine at the end (2 regions, write + RMW).
#define LOADKV(S, st)                                                        \
    {                                                                        \
        const _Float16* kp_ = Kp + (size_t)(st) * 2048;                      \
        S##k00 = *(const half8*)(kp_);                                       \
        S##k01 = *(const half8*)(kp_ + 32);                                  \
        S##k10 = *(const half8*)(kp_ + 1024);                                \
        S##k11 = *(const half8*)(kp_ + 1024 + 32);                           \
        const _Float16* vp_ = Vp + (st) * 32;                                \
        _Pragma("unroll") for (int dt = 0; dt < 4; dt++) {                   \
            S##v[dt][0] = *(const half4*)(vp_ + dt * 16 * Ndim);             \
            S##v[dt][1] = *(const half4*)(vp_ + dt * 16 * Ndim + 16);        \
        }                                                                    \
    }

#define COMPUTE(S)                                                                        \
    {                                                                                     \
        _Pragma("unroll") for (int qi = 0; qi < 4; qi++) {                                \
            f32x4 s0 = {SINIT, SINIT, SINIT, SINIT}, s1 = s0;                             \
            s0 = __builtin_amdgcn_mfma_f32_16x16x32_f16(S##k00, qf0[qi], s0, 0, 0, 0);    \
            s0 = __builtin_amdgcn_mfma_f32_16x16x32_f16(S##k01, qf1[qi], s0, 0, 0, 0);    \
            s1 = __builtin_amdgcn_mfma_f32_16x16x32_f16(S##k10, qf0[qi], s1, 0, 0, 0);    \
            s1 = __builtin_amdgcn_mfma_f32_16x16x32_f16(S##k11, qf1[qi], s1, 0, 0, 0);    \
            half4 alo, ahi;                                                               \
            float rs = 0.f;                                                               \
            _Pragma("unroll") for (int r = 0; r < 4; r++) {                               \
                float e0 = __builtin_exp2f(s0[r]);                                        \
                float e1 = __builtin_exp2f(s1[r]);                                        \
                rs += e0 + e1;                                                            \
                alo[r] = (_Float16)e0;                                                    \
                ahi[r] = (_Float16)e1;                                                    \
            }                                                                             \
            lr[qi] += rs;                                                                 \
            _Pragma("unroll") for (int dt = 0; dt < 4; dt++) {                            \
                oa[qi][dt] = __builtin_amdgcn_mfma_f32_16x16x16f16(alo, S##v[dt][0],      \
                                                                   oa[qi][dt], 0, 0, 0); \
                oa[qi][dt] = __builtin_amdgcn_mfma_f32_16x16x16f16(ahi, S##v[dt][1],      \
                                                                   oa[qi][dt], 0, 0, 0); \
            }                                                                             \
        }                                                                                 \
    }

__global__ __launch_bounds__(256, 2) void attn_k(const _Float16* __restrict__ qT,
                                                 const _Float16* __restrict__ kT,
                                                 const _Float16* __restrict__ vF,
                                                 float* __restrict__ outp) {
    __shared__ __align__(16) char smem[33792];  // 2x16KB O-combine + 1KB lr
    const int tid = threadIdx.x;
    const int w = tid >> 6, lane = tid & 63;
    const int a = lane >> 4, b_ = lane & 15;
    const int s = blockIdx.x;
    const int o = ((s & 7) << 6) + (s >> 3);
    const int qt = o & 63;
    const size_t bh = (size_t)(o >> 6);
    const int q0 = qt << 6;
    const _Float16* Qb = qT + bh * (size_t)(Ndim * 64);
    const _Float16* Kb = kT + bh * (size_t)(Ndim * 64);
    const _Float16* Vb = vF + bh * (size_t)(64 * Ndim);

    // Q fragments for all 4 q-tiles (scale folded)
    half8 qf0[4], qf1[4];
#pragma unroll
    for (int qi = 0; qi < 4; qi++) {
        const _Float16* qp = Qb + (size_t)(q0 + qi * 16 + b_) * 64 + a * 8;
        qf0[qi] = *(const half8*)(qp);
        qf1[qi] = *(const half8*)(qp + 32);
    }

    const int kb = w << 10;  // this wave's key-range base
    const _Float16* Kp = Kb + (size_t)(kb + b_) * 64 + a * 8;
    const _Float16* Vp = Vb + (size_t)b_ * Ndim + kb + a * 4;

    f32x4 oa[4][4] = {};
    float lr[4] = {0.f, 0.f, 0.f, 0.f};

    half8 Ak00, Ak01, Ak10, Ak11; half4 Av[4][2];
    half8 Bk00, Bk01, Bk10, Bk11; half4 Bv[4][2];

    LOADKV(A, 0);
    for (int st = 0; st < 32; st += 2) {
        LOADKV(B, st + 1);
        COMPUTE(A);
        if (st + 2 < 32) LOADKV(A, st + 2);
        COMPUTE(B);
    }

    // in-wave lr reduce -> full per-wave row-sum for q = qi*16 + b_
    float lrw[4];
#pragma unroll
    for (int qi = 0; qi < 4; qi++) {
        float t = lr[qi];
        t += __shfl_xor(t, 16);
        t += __shfl_xor(t, 32);
        lrw[qi] = t;
    }
    float* lrs = (float*)(smem + 32768);  // [4 waves][64 q]
    if (a == 0) {
#pragma unroll
        for (int qi = 0; qi < 4; qi++) lrs[w * 64 + qi * 16 + b_] = lrw[qi];
    }

    // O combine: waves 0,1 write regions 0,1; waves 2,3 add into them.
    // element (d = 16dt+b_, q = qi*16+4a+r) stored at float off d*64 + u*4,
    // u = (qi*4+a) ^ b_  (XOR keeps all 32 banks busy)
    float* Ow = (float*)(smem + ((w & 1) << 14));
    if (w < 2) {
#pragma unroll
        for (int qi = 0; qi < 4; qi++)
#pragma unroll
            for (int dt = 0; dt < 4; dt++) {
                int off = (16 * dt + b_) * 64 + (((qi * 4 + a) ^ b_) << 2);
                *(f32x4*)(Ow + off) = oa[qi][dt];
            }
    }
    __syncthreads();
    if (w >= 2) {
#pragma unroll
        for (int qi = 0; qi < 4; qi++)
#pragma unroll
            for (int dt = 0; dt < 4; dt++) {
                int off = (16 * dt + b_) * 64 + (((qi * 4 + a) ^ b_) << 2);
                f32x4 v = *(const f32x4*)(Ow + off);
                v += oa[qi][dt];
                *(f32x4*)(Ow + off) = v;
            }
    }
    __syncthreads();

    // final: sum 2 regions, normalize, coalesced store of O^T[d][q]
    {
        const float* R0 = (const float*)(smem);
        const float* R1 = (const float*)(smem + 16384);
        int dr = tid >> 4, qc = tid & 15;
        f32x4 lt = *(const f32x4*)(lrs + qc * 4);
        lt += *(const f32x4*)(lrs + 64 + qc * 4);
        lt += *(const f32x4*)(lrs + 128 + qc * 4);
        lt += *(const f32x4*)(lrs + 192 + qc * 4);
        f32x4 inv;
#pragma unroll
        for (int r = 0; r < 4; r++) inv[r] = 1.0f / lt[r];
#pragma unroll
        for (int p = 0; p < 4; p++) {
            int d = p * 16 + dr;
            int off = d * 64 + ((qc ^ (d & 15)) << 2);
            f32x4 v = *(const f32x4*)(R0 + off);
            v += *(const f32x4*)(R1 + off);
#pragma unroll
            for (int r = 0; r < 4; r++) v[r] *= inv[r];
            *(f32x4*)(outp + (bh * 64 + d) * (size_t)Ndim + q0 + (qc << 2)) = v;
        }
    }
}

// ---------------- proj GEMM (fp32) with bias+residual epilogue ----------------
__global__ __launch_bounds__(256) void gemm_proj_k(const float* __restrict__ WT,
                                                   const float* __restrict__ X,
                                                   float* __restrict__ out,
                                                   const float* __restrict__ bias,
                                                   const float* __restrict__ resid) {
    __shared__ __align__(16) float Ws[32][128];
    __shared__ __align__(16) float Xs[32][128];
    const int tid = threadIdx.x, tx = tid & 15, ty = tid >> 4;
    const int n0 = blockIdx.x << 7, o0 = blockIdx.y << 7;
    const size_t bX = (size_t)blockIdx.z * Cdim * Ndim;
    float acc[8][8] = {};
    for (int k0 = 0; k0 < Cdim; k0 += 32) {
        __syncthreads();
#pragma unroll
        for (int kq = 0; kq < 4; kq++) {
            int f4 = tid + (kq << 8);
            int r = f4 >> 5, cc = (f4 & 31) << 2;
            *(float4*)&Ws[r][cc] = *(const float4*)(WT + (size_t)(k0 + r) * 256 + o0 + cc);
            *(float4*)&Xs[r][cc] = *(const float4*)(X + bX + (size_t)(k0 + r) * Ndim + n0 + cc);
        }
        __syncthreads();
#pragma unroll 4
        for (int kk = 0; kk < 32; kk++) {
            float4 wa = *(const float4*)&Ws[kk][ty << 2];
            float4 wb = *(const float4*)&Ws[kk][(ty << 2) + 64];
            float4 xa = *(const float4*)&Xs[kk][tx << 2];
            float4 xb = *(const float4*)&Xs[kk][(tx << 2) + 64];
            float wv[8] = {wa.x, wa.y, wa.z, wa.w, wb.x, wb.y, wb.z, wb.w};
            float xv[8] = {xa.x, xa.y, xa.z, xa.w, xb.x, xb.y, xb.z, xb.w};
#pragma unroll
            for (int i = 0; i < 8; i++)
#pragma unroll
                for (int j = 0; j < 8; j++)
                    acc[i][j] = fmaf(wv[i], xv[j], acc[i][j]);
        }
    }
#pragma unroll
    for (int i = 0; i < 8; i++) {
        int o = o0 + (ty << 2) + ((i < 4) ? i : (64 + i - 4));
        size_t rowoff = bX + (size_t)o * Ndim + n0 + (tx << 2);
        float bv = bias[o];
        float4 r0, r1;
        r0.x = acc[i][0] + bv; r0.y = acc[i][1] + bv; r0.z = acc[i][2] + bv; r0.w = acc[i][3] + bv;
        r1.x = acc[i][4] + bv; r1.y = acc[i][5] + bv; r1.z = acc[i][6] + bv; r1.w = acc[i][7] + bv;
        float4 x0 = *(const float4*)(resid + rowoff);
        float4 x1 = *(const float4*)(resid + rowoff + 64);
        r0.x += x0.x; r0.y += x0.y; r0.z += x0.z; r0.w += x0.w;
        r1.x += x1.x; r1.y += x1.y; r1.z += x1.z; r1.w += x1.w;
        *(float4*)(out + rowoff) = r0;
        *(float4*)(out + rowoff + 64) = r1;
    }
}

extern "C" void kernel_launch(void* const* d_in, const int* in_sizes, int n_in,
                              void* d_out, int out_size, void* d_ws, size_t ws_size,
                              hipStream_t stream) {
    (void)in_sizes; (void)n_in; (void)out_size; (void)ws_size;
    const float* x        = (const float*)d_in[0];
    const float* gn_scale = (const float*)d_in[1];
    const float* gn_bias  = (const float*)d_in[2];
    const float* w_qkv    = (const float*)d_in[3];
    const float* w_proj   = (const float*)d_in[4];
    const float* b_proj   = (const float*)d_in[5];
    float* ws    = (float*)d_ws;
    float* stats = ws + WS_STATS;
    float* wtp   = ws + WS_WTPROJ;
    _Float16* whq = (_Float16*)(ws + WS_WHQ);
    float* hn    = ws + WS_HN;
    _Float16* hnT = (_Float16*)(ws + WS_HNT);
    _Float16* qT = (_Float16*)(ws + WS_QT);
    _Float16* kT = (_Float16*)(ws + WS_KT);
    _Float16* vF = (_Float16*)(ws + WS_VF);
    float* outp  = (float*)d_out;

    gn_stats_k<<<64, 256, 0, stream>>>(x, stats);
    gnT_k<<<dim3(64, 4, 2), 256, 0, stream>>>(x, stats, gn_scale, gn_bias, hnT);
    wcvt_k<<<768, 256, 0, stream>>>(w_qkv, whq);
    tpose_k<<<dim3(8, 8), dim3(32, 8), 0, stream>>>(w_proj, wtp, 256, 256);
    gemm_qkv16_k<<<dim3(32, 6, 2), 256, 0, stream>>>(whq, hnT, qT, kT, vF);
    attn_k<<<512, 256, 0, stream>>>(qT, kT, vF, hn);
    gemm_proj_k<<<dim3(32, 2, 2), 256, 0, stream>>>(wtp, hn, outp, b_proj, x);
}

// Round 11
// 193.797 us; speedup vs baseline: 1.1968x; 1.1968x over previous
//
#include <hip/hip_runtime.h>
#include <hip/hip_bf16.h>
#include <math.h>

#define Bdim 2
#define Cdim 256
#define Ndim 4096
#define HEADS 4
#define HDim 64

typedef _Float16 half8 __attribute__((ext_vector_type(8)));
typedef _Float16 half4 __attribute__((ext_vector_type(4)));
typedef float f32x4 __attribute__((ext_vector_type(4)));

// ws layout in floats
static const size_t WS_STATS  = 0;        // 64*2 -> pad 256
static const size_t WS_WTPROJ = 256;      // 256*256 f32 -> ends 65792
static const size_t WS_WHQ    = 65792;    // 768*256 f16 = 98304 fl -> ends 164096
static const size_t WS_HN     = 164096;   // 2*256*4096 f32 (attn out) -> ends 2261248
static const size_t WS_HNT    = 2261248;  // 2*4096*256 f16 -> ends 3309824
static const size_t WS_QT     = 3309824;  // 2*4*4096*64 f16 -> ends 4358400
static const size_t WS_KPK    = 4358400;  // packed K fragments -> ends 5406976
static const size_t WS_VPK    = 5406976;  // packed V fragments -> ends 6455552 (~25.8 MB)

// q scale: 1/sqrt(64) * log2(e); MFMA acc init -8.65617 gives P = e^(S_true-6),
// the e^-6 cancels in the normalize.
#define QSCALE 0.18033688f
#define SINIT  -8.65617025f

// ---------------- group-norm stats ----------------
__global__ __launch_bounds__(256) void gn_stats_k(const float* __restrict__ x,
                                                  float* __restrict__ stats) {
    int g = blockIdx.x;
    const float4* p4 = (const float4*)(x + (size_t)g * 32768);
    int tid = threadIdx.x;
    float s = 0.f, ss = 0.f;
#pragma unroll 8
    for (int w = 0; w < 32; w++) {
        float4 v = p4[tid + w * 256];
        s += v.x + v.y + v.z + v.w;
        ss += v.x * v.x + v.y * v.y + v.z * v.z + v.w * v.w;
    }
#pragma unroll
    for (int m = 1; m < 64; m <<= 1) {
        s += __shfl_xor(s, m);
        ss += __shfl_xor(ss, m);
    }
    __shared__ float ws_s[4], ws_ss[4];
    int wid = tid >> 6, lane = tid & 63;
    if (lane == 0) { ws_s[wid] = s; ws_ss[wid] = ss; }
    __syncthreads();
    if (tid == 0) {
        float ts = ws_s[0] + ws_s[1] + ws_s[2] + ws_s[3];
        float tss = ws_ss[0] + ws_ss[1] + ws_ss[2] + ws_ss[3];
        float mean = ts * (1.0f / 32768.0f);
        float var = tss * (1.0f / 32768.0f) - mean * mean;
        stats[2 * g] = mean;
        stats[2 * g + 1] = rsqrtf(var + 1e-5f);
    }
}

// ---------------- GN apply + transpose -> hnT[b][n][c] f16 ----------------
__global__ __launch_bounds__(256) void gnT_k(const float* __restrict__ x,
                                             const float* __restrict__ stats,
                                             const float* __restrict__ scale,
                                             const float* __restrict__ bias,
                                             _Float16* __restrict__ hnT) {
    __shared__ float t[64][68];
    const int tid = threadIdx.x;
    const int n0 = blockIdx.x << 6, c0 = blockIdx.y << 6, bz = blockIdx.z;
    const int cr = tid >> 2, q4 = tid & 3;
    const int c = c0 + cr;
    const int g = bz * 32 + (c >> 3);
    const float sc = stats[2 * g + 1] * scale[c];
    const float bi = bias[c] - stats[2 * g] * sc;
    const float* base = x + ((size_t)(bz * 256 + c)) * Ndim + n0;
#pragma unroll
    for (int k = 0; k < 4; k++) {
        int j = k * 4 + q4;
        float4 v = *(const float4*)(base + j * 4);
        v.x = v.x * sc + bi; v.y = v.y * sc + bi; v.z = v.z * sc + bi; v.w = v.w * sc + bi;
        *(float4*)&t[cr][j * 4] = v;
    }
    __syncthreads();
    const int nr = tid >> 2, ch = tid & 3;
    half8 o0, o1;
#pragma unroll
    for (int j = 0; j < 8; j++) o0[j] = (_Float16)t[ch * 16 + j][nr];
#pragma unroll
    for (int j = 0; j < 8; j++) o1[j] = (_Float16)t[ch * 16 + 8 + j][nr];
    _Float16* dst = hnT + ((size_t)bz * Ndim + n0 + nr) * 256 + c0 + ch * 16;
    *(half8*)(dst) = o0;
    *(half8*)(dst + 8) = o1;
}

// ---------------- w_qkv f32 -> f16 (QSCALE folded for q rows) ----------------
__global__ __launch_bounds__(256) void wcvt_k(const float* __restrict__ w,
                                              _Float16* __restrict__ wh) {
    int i = blockIdx.x * 256 + threadIdx.x;
    float v = w[i];
    if ((i >> 8) < 256) v *= QSCALE;
    wh[i] = (_Float16)v;
}

// ---------------- weight transpose (w_proj only): W[O][C] -> WT[C][O] --------
__global__ __launch_bounds__(256) void tpose_k(const float* __restrict__ W,
                                               float* __restrict__ WT,
                                               int O, int Cc) {
    __shared__ float t[32][33];
    int c0 = blockIdx.x * 32, o0 = blockIdx.y * 32;
    int tx = threadIdx.x, ty = threadIdx.y;
#pragma unroll
    for (int k = 0; k < 4; k++) {
        int o = o0 + ty + k * 8;
        t[ty + k * 8][tx] = W[(size_t)o * Cc + c0 + tx];
    }
    __syncthreads();
#pragma unroll
    for (int k = 0; k < 4; k++) {
        int c = c0 + ty + k * 8;
        WT[(size_t)c * O + o0 + tx] = t[tx][ty + k * 8];
    }
}

// ---------------- QKV GEMM, f16 MFMA; K/V written in attn-fragment order -----
// Packed layouts per (b,h) [262144 halves]:
//  kpk: frag f (0=rows m0..15/cols 0..31, 1=rows/cols 32.., 2=rows+16/cols 0..31,
//       3=rows+16/cols 32..): half8 at (sg*4+f)*512 + lane*8, lane=a*16+b_
//       holds K[sg*32 + (f>=2?16:0) + b_][(f&1)*32 + a*8 .. +7]
//  vpk: half4 at (sg*8+dt*2+sub)*256 + lane*4 + i holds
//       V[dt*16 + b_][sg*32 + sub*16 + a*4 + i]
__global__ __launch_bounds__(256) void gemm_qkv16_k(const _Float16* __restrict__ wh,
                                                    const _Float16* __restrict__ hnT,
                                                    _Float16* __restrict__ qT,
                                                    _Float16* __restrict__ kpk,
                                                    _Float16* __restrict__ vpk) {
    __shared__ __align__(16) char smem[32768];  // W dbuf 2x8K @0, X dbuf 2x8K @16384
    const int tid = threadIdx.x, w = tid >> 6, lane = tid & 63;
    const int a = lane >> 4, b_ = lane & 15;
    const int wo = w >> 1, wn = w & 1;
    const int n0 = blockIdx.x << 7, o0 = blockIdx.y << 7, bz = blockIdx.z;

    const int srow = tid >> 1, su = (tid & 1) << 1;
    const _Float16* wg = wh + (size_t)(o0 + srow) * 256 + (su << 3);
    const _Float16* xg = hnT + ((size_t)(bz * Ndim + n0 + srow)) * 256 + (su << 3);
    const int wd0 = srow * 64 + ((su ^ (srow & 3)) << 4);
    const int wd1 = srow * 64 + (((su + 1) ^ (srow & 3)) << 4);

    {
        half8 a0 = *(const half8*)(wg), a1 = *(const half8*)(wg + 8);
        half8 b0 = *(const half8*)(xg), b1 = *(const half8*)(xg + 8);
        *(half8*)(smem + wd0) = a0; *(half8*)(smem + wd1) = a1;
        *(half8*)(smem + 16384 + wd0) = b0; *(half8*)(smem + 16384 + wd1) = b1;
    }
    __syncthreads();

    f32x4 acc[4][4] = {};
    const int fa = (a ^ (b_ & 3)) << 4;
    int arow[4], brow[4];
#pragma unroll
    for (int t = 0; t < 4; t++) {
        arow[t] = (wo * 64 + t * 16 + b_) * 64 + fa;
        brow[t] = 16384 + (wn * 64 + t * 16 + b_) * 64 + fa;
    }

    for (int kk = 0; kk < 8; kk++) {
        const int cur = (kk & 1) * 8192;
        half8 nw0, nw1, nx0, nx1;
        const bool pf = (kk < 7);
        if (pf) {
            const _Float16* wp = wg + (kk + 1) * 32;
            const _Float16* xp = xg + (kk + 1) * 32;
            nw0 = *(const half8*)(wp); nw1 = *(const half8*)(wp + 8);
            nx0 = *(const half8*)(xp); nx1 = *(const half8*)(xp + 8);
        }
        half8 af[4], bf[4];
#pragma unroll
        for (int t = 0; t < 4; t++) {
            af[t] = *(const half8*)(smem + cur + arow[t]);
            bf[t] = *(const half8*)(smem + cur + brow[t]);
        }
#pragma unroll
        for (int i = 0; i < 4; i++)
#pragma unroll
            for (int j = 0; j < 4; j++)
                acc[i][j] = __builtin_amdgcn_mfma_f32_16x16x32_f16(af[i], bf[j], acc[i][j], 0, 0, 0);
        if (pf) {
            const int nxt = cur ^ 8192;
            *(half8*)(smem + nxt + wd0) = nw0; *(half8*)(smem + nxt + wd1) = nw1;
            *(half8*)(smem + 16384 + nxt + wd0) = nx0; *(half8*)(smem + 16384 + nxt + wd1) = nx1;
        }
        __syncthreads();
    }

    if (o0 < 512) {
        // q/k: LDS-bounce to [n][o] f16 (8B-unit XOR swizzle) first
#pragma unroll
        for (int ot = 0; ot < 4; ot++) {
#pragma unroll
            for (int nt = 0; nt < 4; nt++) {
                int n = wn * 64 + nt * 16 + b_;
                int u = wo * 16 + ot * 4 + a;
                half4 hv;
                hv[0] = (_Float16)acc[ot][nt][0]; hv[1] = (_Float16)acc[ot][nt][1];
                hv[2] = (_Float16)acc[ot][nt][2]; hv[3] = (_Float16)acc[ot][nt][3];
                *(half4*)(smem + n * 256 + ((u ^ (n & 31)) << 3)) = hv;
            }
        }
        __syncthreads();
        const int headbase = (o0 >> 6) & 3;
        const bool isq = (o0 < 256);
#pragma unroll
        for (int hsel = 0; hsel < 2; hsel++) {
            const int bhh = bz * 4 + headbase + hsel;
#pragma unroll
            for (int p = 0; p < 4; p++) {
                int n = p * 32 + (tid >> 3), j = tid & 7;
                int u0 = hsel * 16 + j * 2;
                half4 lo = *(const half4*)(smem + n * 256 + ((u0 ^ (n & 31)) << 3));
                half4 hi = *(const half4*)(smem + n * 256 + (((u0 + 1) ^ (n & 31)) << 3));
                half8 o8;
                o8[0] = lo[0]; o8[1] = lo[1]; o8[2] = lo[2]; o8[3] = lo[3];
                o8[4] = hi[0]; o8[5] = hi[1]; o8[6] = hi[2]; o8[7] = hi[3];
                int n_g = n0 + n;
                if (isq) {
                    *(half8*)(qT + (size_t)bhh * (Ndim * 64) + (size_t)n_g * 64 + j * 8) = o8;
                } else {
                    int sg = n_g >> 5, nm = n_g & 31;
                    int f = ((nm >> 4) << 1) | (j >> 2);
                    int off = sg * 2048 + f * 512 + (((j & 3) << 4) | (nm & 15)) * 8;
                    *(half8*)(kpk + (size_t)bhh * 262144 + off) = o8;
                }
            }
        }
    } else {
        // v: scatter into packed fragment order (128B segments per (ot,nt,r) set)
        const int rowbase = (o0 - 512) + wo * 64;  // multiple of 64
        const int hh = rowbase >> 6;
        _Float16* vb = vpk + (size_t)(bz * 4 + hh) * 262144;
        const int i_ = b_ & 3, aslot = b_ >> 2;
#pragma unroll
        for (int ot = 0; ot < 4; ot++) {
#pragma unroll
            for (int nt = 0; nt < 4; nt++) {
                int n_g = n0 + wn * 64 + nt * 16;  // + b_ ; b_ only affects (aslot,i_)
                int sg = n_g >> 5, sub = (n_g >> 4) & 1;
                int base = sg * 2048 + (ot * 2 + sub) * 256 + (aslot << 6) + i_;
#pragma unroll
                for (int r = 0; r < 4; r++)
                    vb[base + (a * 4 + r) * 4] = (_Float16)acc[ot][nt][r];
            }
        }
    }
}

// ---------------- flash attention: register-direct packed K/V ----------------
// 512 blocks (XCD-swizzled). Wave w owns keys [w*1024,(w+1)*1024) x ALL 64 q.
// All loads are fully coalesced packed fragments (K: 4x1KB, V: 8x512B per step).
// NO LDS and NO barriers in the main loop; one-time LDS combine at the end.
#define LOADKV(S, st)                                                        \
    {                                                                        \
        const _Float16* kp_ = Kp + (size_t)(st) * 2048;                      \
        S##k00 = *(const half8*)(kp_);                                       \
        S##k01 = *(const half8*)(kp_ + 512);                                 \
        S##k10 = *(const half8*)(kp_ + 1024);                                \
        S##k11 = *(const half8*)(kp_ + 1536);                                \
        const _Float16* vp_ = Vp + (size_t)(st) * 2048;                      \
        _Pragma("unroll") for (int dt = 0; dt < 4; dt++) {                   \
            S##v[dt][0] = *(const half4*)(vp_ + (dt * 2 + 0) * 256);         \
            S##v[dt][1] = *(const half4*)(vp_ + (dt * 2 + 1) * 256);         \
        }                                                                    \
    }

#define COMPUTE(S)                                                                        \
    {                                                                                     \
        _Pragma("unroll") for (int qi = 0; qi < 4; qi++) {                                \
            f32x4 s0 = {SINIT, SINIT, SINIT, SINIT}, s1 = s0;                             \
            s0 = __builtin_amdgcn_mfma_f32_16x16x32_f16(S##k00, qf0[qi], s0, 0, 0, 0);    \
            s0 = __builtin_amdgcn_mfma_f32_16x16x32_f16(S##k01, qf1[qi], s0, 0, 0, 0);    \
            s1 = __builtin_amdgcn_mfma_f32_16x16x32_f16(S##k10, qf0[qi], s1, 0, 0, 0);    \
            s1 = __builtin_amdgcn_mfma_f32_16x16x32_f16(S##k11, qf1[qi], s1, 0, 0, 0);    \
            half4 alo, ahi;                                                               \
            float rs = 0.f;                                                               \
            _Pragma("unroll") for (int r = 0; r < 4; r++) {                               \
                float e0 = __builtin_exp2f(s0[r]);                                        \
                float e1 = __builtin_exp2f(s1[r]);                                        \
                rs += e0 + e1;                                                            \
                alo[r] = (_Float16)e0;                                                    \
                ahi[r] = (_Float16)e1;                                                    \
            }                                                                             \
            lr[qi] += rs;                                                                 \
            _Pragma("unroll") for (int dt = 0; dt < 4; dt++) {                            \
                oa[qi][dt] = __builtin_amdgcn_mfma_f32_16x16x16f16(alo, S##v[dt][0],      \
                                                                   oa[qi][dt], 0, 0, 0); \
                oa[qi][dt] = __builtin_amdgcn_mfma_f32_16x16x16f16(ahi, S##v[dt][1],      \
                                                                   oa[qi][dt], 0, 0, 0); \
            }                                                                             \
        }                                                                                 \
    }

__global__ __launch_bounds__(256, 2) void attn_k(const _Float16* __restrict__ qT,
                                                 const _Float16* __restrict__ kpk,
                                                 const _Float16* __restrict__ vpk,
                                                 float* __restrict__ outp) {
    __shared__ __align__(16) char smem[33792];  // 2x16KB O-combine + 1KB lr
    const int tid = threadIdx.x;
    const int w = tid >> 6, lane = tid & 63;
    const int a = lane >> 4, b_ = lane & 15;
    const int s = blockIdx.x;
    const int o = ((s & 7) << 6) + (s >> 3);
    const int qt = o & 63;
    const size_t bh = (size_t)(o >> 6);
    const int q0 = qt << 6;
    const _Float16* Qb = qT + bh * (size_t)(Ndim * 64);

    // Q fragments for all 4 q-tiles (scale folded)
    half8 qf0[4], qf1[4];
#pragma unroll
    for (int qi = 0; qi < 4; qi++) {
        const _Float16* qp = Qb + (size_t)(q0 + qi * 16 + b_) * 64 + a * 8;
        qf0[qi] = *(const half8*)(qp);
        qf1[qi] = *(const half8*)(qp + 32);
    }

    // wave's key range: sg = w*32 + st
    const _Float16* Kp = kpk + bh * 262144 + (size_t)(w * 32) * 2048 + (size_t)lane * 8;
    const _Float16* Vp = vpk + bh * 262144 + (size_t)(w * 32) * 2048 + (size_t)lane * 4;

    f32x4 oa[4][4] = {};
    float lr[4] = {0.f, 0.f, 0.f, 0.f};

    half8 Ak00, Ak01, Ak10, Ak11; half4 Av[4][2];
    half8 Bk00, Bk01, Bk10, Bk11; half4 Bv[4][2];

    LOADKV(A, 0);
    for (int st = 0; st < 32; st += 2) {
        LOADKV(B, st + 1);
        COMPUTE(A);
        if (st + 2 < 32) LOADKV(A, st + 2);
        COMPUTE(B);
    }

    // in-wave lr reduce -> full per-wave row-sum for q = qi*16 + b_
    float lrw[4];
#pragma unroll
    for (int qi = 0; qi < 4; qi++) {
        float t = lr[qi];
        t += __shfl_xor(t, 16);
        t += __shfl_xor(t, 32);
        lrw[qi] = t;
    }
    float* lrs = (float*)(smem + 32768);  // [4 waves][64 q]
    if (a == 0) {
#pragma unroll
        for (int qi = 0; qi < 4; qi++) lrs[w * 64 + qi * 16 + b_] = lrw[qi];
    }

    // O combine: waves 0,1 write regions 0,1; waves 2,3 add into them.
    float* Ow = (float*)(smem + ((w & 1) << 14));
    if (w < 2) {
#pragma unroll
        for (int qi = 0; qi < 4; qi++)
#pragma unroll
            for (int dt = 0; dt < 4; dt++) {
                int off = (16 * dt + b_) * 64 + (((qi * 4 + a) ^ b_) << 2);
                *(f32x4*)(Ow + off) = oa[qi][dt];
            }
    }
    __syncthreads();
    if (w >= 2) {
#pragma unroll
        for (int qi = 0; qi < 4; qi++)
#pragma unroll
            for (int dt = 0; dt < 4; dt++) {
                int off = (16 * dt + b_) * 64 + (((qi * 4 + a) ^ b_) << 2);
                f32x4 v = *(const f32x4*)(Ow + off);
                v += oa[qi][dt];
                *(f32x4*)(Ow + off) = v;
            }
    }
    __syncthreads();

    // final: sum 2 regions, normalize, coalesced store of O^T[d][q]
    {
        const float* R0 = (const float*)(smem);
        const float* R1 = (const float*)(smem + 16384);
        int dr = tid >> 4, qc = tid & 15;
        f32x4 lt = *(const f32x4*)(lrs + qc * 4);
        lt += *(const f32x4*)(lrs + 64 + qc * 4);
        lt += *(const f32x4*)(lrs + 128 + qc * 4);
        lt += *(const f32x4*)(lrs + 192 + qc * 4);
        f32x4 inv;
#pragma unroll
        for (int r = 0; r < 4; r++) inv[r] = 1.0f / lt[r];
#pragma unroll
        for (int p = 0; p < 4; p++) {
            int d = p * 16 + dr;
            int off = d * 64 + ((qc ^ (d & 15)) << 2);
            f32x4 v = *(const f32x4*)(R0 + off);
            v += *(const f32x4*)(R1 + off);
#pragma unroll
            for (int r = 0; r < 4; r++) v[r] *= inv[r];
            *(f32x4*)(outp + (bh * 64 + d) * (size_t)Ndim + q0 + (qc << 2)) = v;
        }
    }
}

// ---------------- proj GEMM (fp32) with bias+residual epilogue ----------------
__global__ __launch_bounds__(256) void gemm_proj_k(const float* __restrict__ WT,
                                                   const float* __restrict__ X,
                                                   float* __restrict__ out,
                                                   const float* __restrict__ bias,
                                                   const float* __restrict__ resid) {
    __shared__ __align__(16) float Ws[32][128];
    __shared__ __align__(16) float Xs[32][128];
    const int tid = threadIdx.x, tx = tid & 15, ty = tid >> 4;
    const int n0 = blockIdx.x << 7, o0 = blockIdx.y << 7;
    const size_t bX = (size_t)blockIdx.z * Cdim * Ndim;
    float acc[8][8] = {};
    for (int k0 = 0; k0 < Cdim; k0 += 32) {
        __syncthreads();
#pragma unroll
        for (int kq = 0; kq < 4; kq++) {
            int f4 = tid + (kq << 8);
            int r = f4 >> 5, cc = (f4 & 31) << 2;
            *(float4*)&Ws[r][cc] = *(const float4*)(WT + (size_t)(k0 + r) * 256 + o0 + cc);
            *(float4*)&Xs[r][cc] = *(const float4*)(X + bX + (size_t)(k0 + r) * Ndim + n0 + cc);
        }
        __syncthreads();
#pragma unroll 4
        for (int kk = 0; kk < 32; kk++) {
            float4 wa = *(const float4*)&Ws[kk][ty << 2];
            float4 wb = *(const float4*)&Ws[kk][(ty << 2) + 64];
            float4 xa = *(const float4*)&Xs[kk][tx << 2];
            float4 xb = *(const float4*)&Xs[kk][(tx << 2) + 64];
            float wv[8] = {wa.x, wa.y, wa.z, wa.w, wb.x, wb.y, wb.z, wb.w};
            float xv[8] = {xa.x, xa.y, xa.z, xa.w, xb.x, xb.y, xb.z, xb.w};
#pragma unroll
            for (int i = 0; i < 8; i++)
#pragma unroll
                for (int j = 0; j < 8; j++)
                    acc[i][j] = fmaf(wv[i], xv[j], acc[i][j]);
        }
    }
#pragma unroll
    for (int i = 0; i < 8; i++) {
        int o = o0 + (ty << 2) + ((i < 4) ? i : (64 + i - 4));
        size_t rowoff = bX + (size_t)o * Ndim + n0 + (tx << 2);
        float bv = bias[o];
        float4 r0, r1;
        r0.x = acc[i][0] + bv; r0.y = acc[i][1] + bv; r0.z = acc[i][2] + bv; r0.w = acc[i][3] + bv;
        r1.x = acc[i][4] + bv; r1.y = acc[i][5] + bv; r1.z = acc[i][6] + bv; r1.w = acc[i][7] + bv;
        float4 x0 = *(const float4*)(resid + rowoff);
        float4 x1 = *(const float4*)(resid + rowoff + 64);
        r0.x += x0.x; r0.y += x0.y; r0.z += x0.z; r0.w += x0.w;
        r1.x += x1.x; r1.y += x1.y; r1.z += x1.z; r1.w += x1.w;
        *(float4*)(out + rowoff) = r0;
        *(float4*)(out + rowoff + 64) = r1;
    }
}

extern "C" void kernel_launch(void* const* d_in, const int* in_sizes, int n_in,
                              void* d_out, int out_size, void* d_ws, size_t ws_size,
                              hipStream_t stream) {
    (void)in_sizes; (void)n_in; (void)out_size; (void)ws_size;
    const float* x        = (const float*)d_in[0];
    const float* gn_scale = (const float*)d_in[1];
    const float* gn_bias  = (const float*)d_in[2];
    const float* w_qkv    = (const float*)d_in[3];
    const float* w_proj   = (const float*)d_in[4];
    const float* b_proj   = (const float*)d_in[5];
    float* ws    = (float*)d_ws;
    float* stats = ws + WS_STATS;
    float* wtp   = ws + WS_WTPROJ;
    _Float16* whq = (_Float16*)(ws + WS_WHQ);
    float* hn    = ws + WS_HN;
    _Float16* hnT = (_Float16*)(ws + WS_HNT);
    _Float16* qT = (_Float16*)(ws + WS_QT);
    _Float16* kpk = (_Float16*)(ws + WS_KPK);
    _Float16* vpk = (_Float16*)(ws + WS_VPK);
    float* outp  = (float*)d_out;

    gn_stats_k<<<64, 256, 0, stream>>>(x, stats);
    gnT_k<<<dim3(64, 4, 2), 256, 0, stream>>>(x, stats, gn_scale, gn_bias, hnT);
    wcvt_k<<<768, 256, 0, stream>>>(w_qkv, whq);
    tpose_k<<<dim3(8, 8), dim3(32, 8), 0, stream>>>(w_proj, wtp, 256, 256);
    gemm_qkv16_k<<<dim3(32, 6, 2), 256, 0, stream>>>(whq, hnT, qT, kpk, vpk);
    attn_k<<<512, 256, 0, stream>>>(qT, kpk, vpk, hn);
    gemm_proj_k<<<dim3(32, 2, 2), 256, 0, stream>>>(wtp, hn, outp, b_proj, x);
}